// Round 6
// baseline (739.807 us; speedup 1.0000x reference)
//
#include <hip/hip_runtime.h>
#include <cmath>

typedef __bf16 bf16x8 __attribute__((ext_vector_type(8)));
typedef float  f32x4  __attribute__((ext_vector_type(4)));

#define ATILE 32768   // one K-tile of A: 256 rows * 128 B (bf16, plain row-major)

__device__ __forceinline__ bf16x8 cvt8(f32x4 a, f32x4 b) {
    bf16x8 r;
    r[0] = (__bf16)a[0]; r[1] = (__bf16)a[1]; r[2] = (__bf16)a[2]; r[3] = (__bf16)a[3];
    r[4] = (__bf16)b[0]; r[5] = (__bf16)b[1]; r[6] = (__bf16)b[2]; r[7] = (__bf16)b[3];
    return r;
}

// A0 = concat(cat,x,hid) bf16, K-tiled [ks][row][64 cols], plain layout.
__global__ __launch_bounds__(256)
void prep_xc(const float* __restrict__ cat, const float* __restrict__ x,
             const float* __restrict__ hid, unsigned char* __restrict__ A0)
{
    int id  = blockIdx.x * 256 + threadIdx.x;
    int row = id >> 9, col = (id & 511) * 8;
    const float* src = (col < 512)  ? cat + (size_t)row * 512 + col
                     : (col < 2048) ? x   + (size_t)row * 1536 + (col - 512)
                                    : hid + (size_t)row * 2048 + (col - 2048);
    f32x4 a = *(const f32x4*)src, b = *(const f32x4*)(src + 4);
    *(bf16x8*)(A0 + (size_t)(col >> 6) * ATILE + row * 128 + (col & 63) * 2) = cvt8(a, b);
}

// Zero-barrier streaming GEMM. 512 thr = 8 waves; wave = (mg = wid>>1) 64 M-rows,
// (sub = wid&1): MODE0 -> gate pair {sub*2, sub*2+1}, MODE1 -> 32-col half.
// MODE 0: 256 blocks x 16 cells; fused LSTM epilogue (LDS used only there).
// MODE 1: 500 blocks x 64 vocab cols.
template <int MODE>
__global__ __launch_bounds__(512, 2)
void gemm_stream(const unsigned char* __restrict__ At,
                 const float* __restrict__ W0, const float* __restrict__ W1,
                 const float* __restrict__ W2, const float* __restrict__ W3,
                 const float* __restrict__ B0, const float* __restrict__ B1,
                 const float* __restrict__ B2, const float* __restrict__ B3,
                 const float* __restrict__ cell,
                 float* __restrict__ out0, float* __restrict__ out1,
                 unsigned char* __restrict__ A1out)
{
    const int tid  = threadIdx.x;
    const int lane = tid & 63;
    const int wid  = tid >> 6;
    const int l15  = lane & 15;
    const int l4   = lane >> 4;
    const int mg   = wid >> 1;
    const int sub  = wid & 1;

    const float *wp0, *wp1;
    int c0 = 0, n0 = 0;
    if constexpr (MODE == 0) {
        c0 = blockIdx.x * 16;
        const float* Wg0 = sub ? W2 : W0;   // gates: 0=f 1=i 2=g 3=o
        const float* Wg1 = sub ? W3 : W1;
        wp0 = Wg0 + (size_t)(c0 + l15) * 4096 + l4 * 8;
        wp1 = Wg1 + (size_t)(c0 + l15) * 4096 + l4 * 8;
    } else {
        n0 = blockIdx.x * 64;
        wp0 = W0 + (size_t)(n0 + sub * 32 + l15) * 4096 + l4 * 8;
        wp1 = wp0 + (size_t)16 * 4096;
    }
    const unsigned char* abase = At + (size_t)(mg * 64 + l15) * 128 + l4 * 16;

    f32x4 acc[4][2] = {};

    auto loadA = [&](int ks, bf16x8 (&af)[2][4]) {
        const unsigned char* p = abase + (size_t)ks * ATILE;
        #pragma unroll
        for (int kk = 0; kk < 2; ++kk)
            #pragma unroll
            for (int m = 0; m < 4; ++m)
                af[kk][m] = *(const bf16x8*)(p + m * 2048 + kk * 64);
    };
    auto loadW = [&](int ks, f32x4 (&ws)[2][2][2]) {   // [ptr][kk][half]
        #pragma unroll
        for (int kk = 0; kk < 2; ++kk) {
            const float* q0 = wp0 + ks * 64 + kk * 32;
            const float* q1 = wp1 + ks * 64 + kk * 32;
            ws[0][kk][0] = *(const f32x4*)q0;
            ws[0][kk][1] = *(const f32x4*)(q0 + 4);
            ws[1][kk][0] = *(const f32x4*)q1;
            ws[1][kk][1] = *(const f32x4*)(q1 + 4);
        }
    };
    auto domfma = [&](bf16x8 (&af)[2][4], f32x4 (&ws)[2][2][2]) {
        #pragma unroll
        for (int kk = 0; kk < 2; ++kk) {
            bf16x8 bw0 = cvt8(ws[0][kk][0], ws[0][kk][1]);
            bf16x8 bw1 = cvt8(ws[1][kk][0], ws[1][kk][1]);
            #pragma unroll
            for (int m = 0; m < 4; ++m) {
                acc[m][0] = __builtin_amdgcn_mfma_f32_16x16x32_bf16(af[kk][m], bw0, acc[m][0], 0, 0, 0);
                acc[m][1] = __builtin_amdgcn_mfma_f32_16x16x32_bf16(af[kk][m], bw1, acc[m][1], 0, 0, 0);
            }
        }
    };

    // depth-2 register pipeline, compile-time-named sets (rule #20)
    bf16x8 afA[2][4], afB[2][4];
    f32x4  wsA[2][2][2], wsB[2][2][2];
    loadA(0, afA); loadW(0, wsA);
    loadA(1, afB); loadW(1, wsB);
    for (int ks = 0; ks < 62; ks += 2) {
        domfma(afA, wsA);
        loadA(ks + 2, afA); loadW(ks + 2, wsA);
        domfma(afB, wsB);
        loadA(ks + 3, afB); loadW(ks + 3, wsB);
    }
    domfma(afA, wsA);
    domfma(afB, wsB);

    if constexpr (MODE == 0) {
        // combine gate pairs across waves via LDS, then fused LSTM elementwise.
        __shared__ float lsf[4 * 256 * 16];   // [gate][row][cell] = 64 KB
        #pragma unroll
        for (int n = 0; n < 2; ++n) {
            const int g = sub * 2 + n;
            #pragma unroll
            for (int m = 0; m < 4; ++m) {
                const int rbase = mg * 64 + m * 16 + l4 * 4;   // C/D: col=l15, row=l4*4+j
                #pragma unroll
                for (int j = 0; j < 4; ++j)
                    lsf[(g * 256 + rbase + j) * 16 + l15] = acc[m][n][j];
            }
        }
        __syncthreads();
        const int row = tid >> 1, ch = (tid & 1) * 8;
        const float* cp = cell + (size_t)row * 4096 + c0 + ch;
        f32x4 cv0 = *(const f32x4*)cp, cv1 = *(const f32x4*)(cp + 4);
        f32x4 rc[2], rh[2]; bf16x8 hb;
        #pragma unroll
        for (int e = 0; e < 8; ++e) {
            const int cidx = ch + e;
            const float fz = lsf[(0 * 256 + row) * 16 + cidx] + B0[c0 + cidx];
            const float iz = lsf[(1 * 256 + row) * 16 + cidx] + B1[c0 + cidx];
            const float gz = lsf[(2 * 256 + row) * 16 + cidx] + B2[c0 + cidx];
            const float oz = lsf[(3 * 256 + row) * 16 + cidx] + B3[c0 + cidx];
            const float f = 1.0f / (1.0f + __expf(-fz));
            const float i = 1.0f / (1.0f + __expf(-iz));
            const float g = tanhf(gz);
            const float o = 1.0f / (1.0f + __expf(-oz));
            const float cvv = (e < 4) ? cv0[e & 3] : cv1[e & 3];
            const float cn = f * cvv + i * g;
            const float hn = o * tanhf(cn);
            rc[e >> 2][e & 3] = cn; rh[e >> 2][e & 3] = hn;
            hb[e] = (__bf16)hn;
        }
        float* cq = out0 + (size_t)row * 4096 + c0 + ch;
        float* hq = out1 + (size_t)row * 4096 + c0 + ch;
        *(f32x4*)cq = rc[0]; *(f32x4*)(cq + 4) = rc[1];
        *(f32x4*)hq = rh[0]; *(f32x4*)(hq + 4) = rh[1];
        *(bf16x8*)(A1out + (size_t)(c0 >> 6) * ATILE + row * 128 + ((c0 & 63) + ch) * 2) = hb;
    } else {
        #pragma unroll
        for (int n = 0; n < 2; ++n) {
            const int col = n0 + sub * 32 + n * 16 + l15;
            const float bias = B0[col];
            #pragma unroll
            for (int m = 0; m < 4; ++m) {
                const int r = mg * 64 + m * 16 + l4 * 4;
                f32x4 v = acc[m][n];
                #pragma unroll
                for (int j = 0; j < 4; ++j)
                    out0[(size_t)(r + j) * 32000 + col] = v[j] + bias;
            }
        }
    }
}

__global__ __launch_bounds__(256)
void logsoftmax_inplace(float* __restrict__ out)
{
    float* row    = out + (size_t)blockIdx.x * 32000;
    const int tid = threadIdx.x;
    __shared__ float redm[4], reds[4];

    float m = -1e30f, s = 0.0f;
    for (int i = tid; i < 8000; i += 256) {
        f32x4 v = *(const f32x4*)(row + i * 4);
        float t = fmaxf(fmaxf(v[0], v[1]), fmaxf(v[2], v[3]));
        float nm = fmaxf(m, t);
        s = s * __expf(m - nm) + __expf(v[0] - nm) + __expf(v[1] - nm)
                               + __expf(v[2] - nm) + __expf(v[3] - nm);
        m = nm;
    }
    #pragma unroll
    for (int off = 32; off; off >>= 1) {
        float om = __shfl_xor(m, off), os = __shfl_xor(s, off);
        float nm = fmaxf(m, om);
        s = s * __expf(m - nm) + os * __expf(om - nm);
        m = nm;
    }
    if ((tid & 63) == 0) { redm[tid >> 6] = m; reds[tid >> 6] = s; }
    __syncthreads();
    {
        float M = fmaxf(fmaxf(redm[0], redm[1]), fmaxf(redm[2], redm[3]));
        float S = reds[0] * __expf(redm[0] - M) + reds[1] * __expf(redm[1] - M)
                + reds[2] * __expf(redm[2] - M) + reds[3] * __expf(redm[3] - M);
        m = M; s = S;
    }
    float lse = m + logf(s);

    for (int i = tid; i < 8000; i += 256) {
        f32x4 v = *(const f32x4*)(row + i * 4);
        v[0] -= lse; v[1] -= lse; v[2] -= lse; v[3] -= lse;
        *(f32x4*)(row + i * 4) = v;
    }
}

extern "C" void kernel_launch(void* const* d_in, const int* in_sizes, int n_in,
                              void* d_out, int out_size, void* d_ws, size_t ws_size,
                              hipStream_t stream)
{
    const float* cat  = (const float*)d_in[0];
    const float* x    = (const float*)d_in[1];
    const float* hid  = (const float*)d_in[2];
    const float* cell = (const float*)d_in[3];
    const float* Wf   = (const float*)d_in[4];
    const float* bf   = (const float*)d_in[5];
    const float* Wi   = (const float*)d_in[6];
    const float* bi   = (const float*)d_in[7];
    const float* Wc   = (const float*)d_in[8];
    const float* bc   = (const float*)d_in[9];
    const float* Wo   = (const float*)d_in[10];
    const float* bo   = (const float*)d_in[11];
    const float* Wout = (const float*)d_in[12];
    const float* bout = (const float*)d_in[13];
    float* out = (float*)d_out;

    // ws: A0 bf16 xc tiles (2MB) | A1 bf16 hidden tiles (2MB)
    unsigned char* A0 = (unsigned char*)d_ws;
    unsigned char* A1 = A0 + (size_t)64 * ATILE;

    // d_out: [logits 256x32000 | cell_new 256x4096 | hidden_new 256x4096]
    float* cnew = out + 8192000;
    float* hnew = out + 9240576;

    prep_xc<<<512, 256, 0, stream>>>(cat, x, hid, A0);
    // gates GEMM + fused LSTM: 256 blocks x (16 cells x 4 gates)
    gemm_stream<0><<<256, 512, 0, stream>>>(A0, Wf, Wi, Wc, Wo, bf, bi, bc, bo,
                                            cell, cnew, hnew, A1);
    // vocab GEMM: 500 blocks x 64 cols
    gemm_stream<1><<<500, 512, 0, stream>>>(A1, Wout, nullptr, nullptr, nullptr,
                                            bout, nullptr, nullptr, nullptr,
                                            nullptr, out, nullptr, nullptr);
    logsoftmax_inplace<<<256, 256, 0, stream>>>(out);
}

// Round 7
// 328.095 us; speedup vs baseline: 2.2549x; 2.2549x over previous
//
#include <hip/hip_runtime.h>
#include <cmath>

typedef __bf16 bf16x8 __attribute__((ext_vector_type(8)));
typedef __bf16 bf16x4 __attribute__((ext_vector_type(4)));
typedef float  f32x4  __attribute__((ext_vector_type(4)));

#define ATILE 32768   // one K-tile of A: 256 rows * 128 B (bf16, plain row-major)

__device__ __forceinline__ bf16x8 cvt8(f32x4 a, f32x4 b) {
    bf16x8 r;
    r[0] = (__bf16)a[0]; r[1] = (__bf16)a[1]; r[2] = (__bf16)a[2]; r[3] = (__bf16)a[3];
    r[4] = (__bf16)b[0]; r[5] = (__bf16)b[1]; r[6] = (__bf16)b[2]; r[7] = (__bf16)b[3];
    return r;
}
__device__ __forceinline__ bf16x4 cvt4(f32x4 a) {
    bf16x4 r;
    r[0] = (__bf16)a[0]; r[1] = (__bf16)a[1]; r[2] = (__bf16)a[2]; r[3] = (__bf16)a[3];
    return r;
}

// A0 = concat(cat,x,hid) bf16, K-tiled [ks][row][64 cols], plain layout.
__global__ __launch_bounds__(256)
void prep_xc(const float* __restrict__ cat, const float* __restrict__ x,
             const float* __restrict__ hid, unsigned char* __restrict__ A0)
{
    int id  = blockIdx.x * 256 + threadIdx.x;
    int row = id >> 9, col = (id & 511) * 8;
    const float* src = (col < 512)  ? cat + (size_t)row * 512 + col
                     : (col < 2048) ? x   + (size_t)row * 1536 + (col - 512)
                                    : hid + (size_t)row * 2048 + (col - 2048);
    f32x4 a = *(const f32x4*)src, b = *(const f32x4*)(src + 4);
    *(bf16x8*)(A0 + (size_t)(col >> 6) * ATILE + row * 128 + (col & 63) * 2) = cvt8(a, b);
}

// Producer/consumer GEMM. 512 thr: waves 0-3 consume (64 M-rows each),
// waves 4-7 produce (stream W global->reg->bf16->LDS, 1KB/row bursts).
// BN=64. Window = 256 K. 16 windows. LDS = 2 x 32KB window buffers.
// MODE 0: gates, 256 blocks x (16 cells x 4 gates interleaved: panel row p ->
//         gate p&3, cell c0+(p>>2)); fused LSTM epilogue via z-in-LDS.
// MODE 1: vocab, 500 blocks x 64 cols; bias epilogue.
template <int MODE>
__global__ __launch_bounds__(512)
void gemm_pc(const unsigned char* __restrict__ At,
             const float* __restrict__ W0, const float* __restrict__ W1,
             const float* __restrict__ W2, const float* __restrict__ W3,
             const float* __restrict__ B0, const float* __restrict__ B1,
             const float* __restrict__ B2, const float* __restrict__ B3,
             const float* __restrict__ cell,
             float* __restrict__ out0, float* __restrict__ out1,
             unsigned char* __restrict__ A1out)
{
    constexpr int NW   = 16;     // windows
    constexpr int RB   = 512;    // window row bytes (256 k * 2B)
    constexpr int WBUF = 64 * RB;                  // 32 KB per buffer

    __shared__ __align__(16) unsigned char lds[2 * WBUF];

    const int tid  = threadIdx.x;
    const int lane = tid & 63;
    const int wid  = tid >> 6;
    const int l15  = lane & 15;
    const int l4   = lane >> 4;

    f32x4 acc[4][4] = {};   // consumer accumulators (union-allocated; producers don't use)

    if (wid < 4) {
        // ---------------- consumers ----------------
        const unsigned char* abase = At + (size_t)(wid * 64 + l15) * 128 + l4 * 16;
        bf16x8 afA[2][4], afB[2][4];
        auto loadA = [&](int ks, bf16x8 (&af)[2][4]) {
            const unsigned char* p = abase + (size_t)ks * ATILE;
            #pragma unroll
            for (int kk = 0; kk < 2; ++kk)
                #pragma unroll
                for (int m = 0; m < 4; ++m)
                    af[kk][m] = *(const bf16x8*)(p + m * 2048 + kk * 64);
        };
        auto tile = [&](const unsigned char* win, int kt, bf16x8 (&af)[2][4]) {
            #pragma unroll
            for (int kk = 0; kk < 2; ++kk) {
                bf16x8 bw[4];
                #pragma unroll
                for (int nf = 0; nf < 4; ++nf) {
                    int row = nf * 16 + l15;
                    bw[nf] = *(const bf16x8*)(win + row * RB +
                               ((kt * 128 + kk * 64 + l4 * 16) ^ ((row & 7) << 4)));
                }
                #pragma unroll
                for (int m = 0; m < 4; ++m)
                    #pragma unroll
                    for (int nf = 0; nf < 4; ++nf)
                        acc[m][nf] = __builtin_amdgcn_mfma_f32_16x16x32_bf16(
                            af[kk][m], bw[nf], acc[m][nf], 0, 0, 0);
            }
        };
        for (int w = 0; w < NW; ++w) {
            __builtin_amdgcn_s_barrier();          // window w buffer ready
            const unsigned char* win = lds + (w & 1) * WBUF;
            loadA(w * 4 + 0, afA);
            loadA(w * 4 + 1, afB);
            tile(win, 0, afA); loadA(w * 4 + 2, afA);
            tile(win, 1, afB); loadA(w * 4 + 3, afB);
            tile(win, 2, afA);
            tile(win, 3, afB);
        }
    } else {
        // ---------------- producers ----------------
        const int pw   = wid - 4;       // 0..3 -> panel rows [pw*16, pw*16+16)
        const int rsub = lane >> 3;     // 0..7 (row within 8-row sweep)
        const int li   = lane & 7;      // 16B-chunk within 128B
        const float* rowp[2];
        #pragma unroll
        for (int rr = 0; rr < 2; ++rr) {
            const int p = pw * 16 + rr * 8 + rsub;
            const float* src;
            if constexpr (MODE == 0) {
                const int gate = p & 3;
                const int cellc = blockIdx.x * 16 + (p >> 2);
                const float* Wg = (gate == 0) ? W0 : (gate == 1) ? W1
                                : (gate == 2) ? W2 : W3;
                src = Wg + (size_t)cellc * 4096;
            } else {
                src = W0 + (size_t)(blockIdx.x * 64 + p) * 4096;
            }
            rowp[rr] = src + li * 4;
        }
        f32x4 wreg[2][8];
        auto issueW = [&](int w) {
            #pragma unroll
            for (int rr = 0; rr < 2; ++rr)
                #pragma unroll
                for (int i = 0; i < 8; ++i)
                    wreg[rr][i] = *(const f32x4*)(rowp[rr] + w * 256 + i * 32);
        };
        auto writeW = [&](int buf) {
            unsigned char* b = lds + buf * WBUF;
            #pragma unroll
            for (int rr = 0; rr < 2; ++rr) {
                const int row = pw * 16 + rr * 8 + rsub;
                unsigned char* rp = b + row * RB;
                const int sw = (row & 7) << 4;
                #pragma unroll
                for (int i = 0; i < 8; ++i)
                    *(bf16x4*)(rp + ((li * 8 + i * 64) ^ sw)) = cvt4(wreg[rr][i]);
            }
        };
        issueW(0);
        __builtin_amdgcn_sched_barrier(0);
        for (int w = 0; w < NW; ++w) {
            writeW(w & 1);                         // compiler inserts vmcnt wait for wreg
            if (w + 1 < NW) issueW(w + 1);         // next window in flight across barrier
            __builtin_amdgcn_sched_barrier(0);
            asm volatile("s_waitcnt lgkmcnt(0)" ::: "memory");
            __builtin_amdgcn_s_barrier();
        }
    }

    if constexpr (MODE == 0) {
        // ---- fused LSTM epilogue (all waves) ----
        __builtin_amdgcn_s_barrier();              // all window reads complete
        float* zl = (float*)lds;                   // 256 rows x 64 cols fp32 = 64 KB
        if (wid < 4) {
            #pragma unroll
            for (int m = 0; m < 4; ++m)
                #pragma unroll
                for (int nf = 0; nf < 4; ++nf)
                    #pragma unroll
                    for (int j = 0; j < 4; ++j)
                        zl[(wid * 64 + m * 16 + l4 * 4 + j) * 64 + nf * 16 + l15] =
                            acc[m][nf][j];
        }
        asm volatile("s_waitcnt lgkmcnt(0)" ::: "memory");
        __builtin_amdgcn_s_barrier();

        const int row = tid >> 1, cg = (tid & 1) * 8;
        const int ccol = blockIdx.x * 16 + cg;
        const float* cp = cell + (size_t)row * 4096 + ccol;
        f32x4 cv0 = *(const f32x4*)cp, cv1 = *(const f32x4*)(cp + 4);
        f32x4 rc[2], rh[2]; bf16x8 hb;
        #pragma unroll
        for (int e = 0; e < 8; ++e) {
            const int c = cg + e;
            const float fz = zl[row * 64 + c * 4 + 0] + B0[ccol + e];
            const float iz = zl[row * 64 + c * 4 + 1] + B1[ccol + e];
            const float gz = zl[row * 64 + c * 4 + 2] + B2[ccol + e];
            const float oz = zl[row * 64 + c * 4 + 3] + B3[ccol + e];
            const float f = 1.0f / (1.0f + __expf(-fz));
            const float i = 1.0f / (1.0f + __expf(-iz));
            const float g = tanhf(gz);
            const float o = 1.0f / (1.0f + __expf(-oz));
            const float cvv = (e < 4) ? cv0[e & 3] : cv1[e & 3];
            const float cn = f * cvv + i * g;
            const float hn = o * tanhf(cn);
            rc[e >> 2][e & 3] = cn; rh[e >> 2][e & 3] = hn;
            hb[e] = (__bf16)hn;
        }
        float* cq = out0 + (size_t)row * 4096 + ccol;
        float* hq = out1 + (size_t)row * 4096 + ccol;
        *(f32x4*)cq = rc[0]; *(f32x4*)(cq + 4) = rc[1];
        *(f32x4*)hq = rh[0]; *(f32x4*)(hq + 4) = rh[1];
        *(bf16x8*)(A1out + (size_t)(ccol >> 6) * ATILE + row * 128 + (ccol & 63) * 2) = hb;
    } else {
        if (wid < 4) {
            const int n0 = blockIdx.x * 64;
            #pragma unroll
            for (int nf = 0; nf < 4; ++nf) {
                const int col = n0 + nf * 16 + l15;
                const float bias = B0[col];
                #pragma unroll
                for (int m = 0; m < 4; ++m) {
                    const int r = wid * 64 + m * 16 + l4 * 4;
                    f32x4 v = acc[m][nf];
                    #pragma unroll
                    for (int j = 0; j < 4; ++j)
                        out0[(size_t)(r + j) * 32000 + col] = v[j] + bias;
                }
            }
        }
    }
}

__global__ __launch_bounds__(256)
void logsoftmax_inplace(float* __restrict__ out)
{
    float* row    = out + (size_t)blockIdx.x * 32000;
    const int tid = threadIdx.x;
    __shared__ float redm[4], reds[4];

    float m = -1e30f, s = 0.0f;
    for (int i = tid; i < 8000; i += 256) {
        f32x4 v = *(const f32x4*)(row + i * 4);
        float t = fmaxf(fmaxf(v[0], v[1]), fmaxf(v[2], v[3]));
        float nm = fmaxf(m, t);
        s = s * __expf(m - nm) + __expf(v[0] - nm) + __expf(v[1] - nm)
                               + __expf(v[2] - nm) + __expf(v[3] - nm);
        m = nm;
    }
    #pragma unroll
    for (int off = 32; off; off >>= 1) {
        float om = __shfl_xor(m, off), os = __shfl_xor(s, off);
        float nm = fmaxf(m, om);
        s = s * __expf(m - nm) + os * __expf(om - nm);
        m = nm;
    }
    if ((tid & 63) == 0) { redm[tid >> 6] = m; reds[tid >> 6] = s; }
    __syncthreads();
    {
        float M = fmaxf(fmaxf(redm[0], redm[1]), fmaxf(redm[2], redm[3]));
        float S = reds[0] * __expf(redm[0] - M) + reds[1] * __expf(redm[1] - M)
                + reds[2] * __expf(redm[2] - M) + reds[3] * __expf(redm[3] - M);
        m = M; s = S;
    }
    float lse = m + logf(s);

    for (int i = tid; i < 8000; i += 256) {
        f32x4 v = *(const f32x4*)(row + i * 4);
        v[0] -= lse; v[1] -= lse; v[2] -= lse; v[3] -= lse;
        *(f32x4*)(row + i * 4) = v;
    }
}

extern "C" void kernel_launch(void* const* d_in, const int* in_sizes, int n_in,
                              void* d_out, int out_size, void* d_ws, size_t ws_size,
                              hipStream_t stream)
{
    const float* cat  = (const float*)d_in[0];
    const float* x    = (const float*)d_in[1];
    const float* hid  = (const float*)d_in[2];
    const float* cell = (const float*)d_in[3];
    const float* Wf   = (const float*)d_in[4];
    const float* bf   = (const float*)d_in[5];
    const float* Wi   = (const float*)d_in[6];
    const float* bi   = (const float*)d_in[7];
    const float* Wc   = (const float*)d_in[8];
    const float* bc   = (const float*)d_in[9];
    const float* Wo   = (const float*)d_in[10];
    const float* bo   = (const float*)d_in[11];
    const float* Wout = (const float*)d_in[12];
    const float* bout = (const float*)d_in[13];
    float* out = (float*)d_out;

    // ws: A0 bf16 xc tiles (2MB) | A1 bf16 hidden tiles (2MB)
    unsigned char* A0 = (unsigned char*)d_ws;
    unsigned char* A1 = A0 + (size_t)64 * ATILE;

    // d_out: [logits 256x32000 | cell_new 256x4096 | hidden_new 256x4096]
    float* cnew = out + 8192000;
    float* hnew = out + 9240576;

    prep_xc<<<512, 256, 0, stream>>>(cat, x, hid, A0);
    // gates GEMM + fused LSTM: 256 blocks x (16 cells x 4 gates)
    gemm_pc<0><<<256, 512, 0, stream>>>(A0, Wf, Wi, Wc, Wo, bf, bi, bc, bo,
                                        cell, cnew, hnew, A1);
    // vocab GEMM: 500 blocks x 64 cols
    gemm_pc<1><<<500, 512, 0, stream>>>(A1, Wout, nullptr, nullptr, nullptr,
                                        bout, nullptr, nullptr, nullptr,
                                        nullptr, out, nullptr, nullptr);
    logsoftmax_inplace<<<256, 256, 0, stream>>>(out);
}